// Round 7
// baseline (303.877 us; speedup 1.0000x reference)
//
#include <hip/hip_runtime.h>

// ---------------------------------------------------------------------------
// Self-attention: out = softmax((xWq)(xWk)^T / sqrt(64)) (xWv)
// B=4, N=4096, Din=128, Dout=64.
//   k0 wprep : W -> hi/lo bf16 planes in MFMA B-frag order (Q-scale folded);
//              also zeroes the split-K counters.
//   k1 qkv   : x@W, wave = 32 rows x 32 cols (3-pass bf16 MFMA), 512 blocks
//              x 384 thr (6 waves) -> 3 waves/SIMD. Epilogue LDS transpose.
//   k2 attn  : flash attention, 32-q waves, nseg=8. K and V double-buffered
//              in LDS via async global_load_lds; v_perm truncating bf16 pack;
//              near-one-hot tile skip; P C->A via shfl_xor(32); fused
//              split-K merge (threadfence + atomic, last block reduces).
// ---------------------------------------------------------------------------

typedef __attribute__((ext_vector_type(8))) short bf16x8;
typedef __attribute__((ext_vector_type(16))) float f32x16;
typedef __attribute__((ext_vector_type(4))) unsigned u32x4;
typedef unsigned short us;

__device__ __forceinline__ us f2bf(float f) {               // RTNE fp32->bf16
  unsigned u = __builtin_bit_cast(unsigned, f);
  u += 0x7FFFu + ((u >> 16) & 1u);
  return (us)(u >> 16);
}
__device__ __forceinline__ float bf2f(us h) {
  unsigned u = ((unsigned)h) << 16;
  return __builtin_bit_cast(float, u);
}
__device__ __forceinline__ f32x16 mfma(bf16x8 a, bf16x8 b, f32x16 c) {
  return __builtin_amdgcn_mfma_f32_32x32x16_bf16(a, b, c, 0, 0, 0);
}
// truncating pack: low16 = bf16_trunc(a), high16 = bf16_trunc(b). ONE v_perm.
__device__ __forceinline__ unsigned pk2t(float a, float b) {
  return __builtin_amdgcn_perm(__builtin_bit_cast(unsigned, b),
                               __builtin_bit_cast(unsigned, a), 0x07060302u);
}
#define EXP2(x) __builtin_amdgcn_exp2f(x)

// async 16B global->LDS DMA: lane i lands at ldsbase + 16*i
__device__ __forceinline__ void gld16(const us* g, us* l) {
  __builtin_amdgcn_global_load_lds(
      (__attribute__((address_space(1))) const unsigned int*)g,
      (__attribute__((address_space(3))) unsigned int*)l, 16, 0, 0);
}

#define NSEG 8
#define ITERS 8

// ---------------------------------------------------------------------------
// Kernel 0: W prep + counter zero. w[3][128][64] fp32 -> Wbh/Wbl bf16 hi/lo,
// B-frag order: idx = ((g*8+ks)*2+h)*256 + (e&31)*8 + j; g=(p*64+e)>>5.
// Plane p==0 pre-scaled by 0.125*log2(e).
// ---------------------------------------------------------------------------
__global__ __launch_bounds__(256, 1) void wprep_kernel(
    const float* __restrict__ w, us* __restrict__ Wbh, us* __restrict__ Wbl,
    int* __restrict__ cnt)
{
  const int i = blockIdx.x * 256 + threadIdx.x;
  if (blockIdx.x == 0) {                     // zero split-K counters (512)
    cnt[threadIdx.x] = 0;
    cnt[threadIdx.x + 256] = 0;
  }
  if (i >= 24576) return;
  const int p = i >> 13, d = (i & 8191) >> 6, e = i & 63;
  float v = w[i];
  if (p == 0) v *= 0.18033688011112042f;
  const us hi = f2bf(v);
  const us lo = f2bf(v - bf2f(hi));
  const int g = (p * 64 + e) >> 5, ks = d >> 4, hh = (d >> 3) & 1, j = d & 7;
  const int o = ((g * 8 + ks) * 2 + hh) * 256 + (e & 31) * 8 + j;
  Wbh[o] = hi;
  Wbl[o] = lo;
}

// ---------------------------------------------------------------------------
// Kernel 1: QKV projection. 512 blocks x 384 thr (6 waves). Block = 32 rows
// x 192 cols; wave wid covers col group wid*32 (= Wb 'g' index). 3 waves/SIMD.
// ---------------------------------------------------------------------------
__global__ __launch_bounds__(384, 1) void qkv_kernel(
    const float* __restrict__ x,
    const us* __restrict__ Wbh, const us* __restrict__ Wbl,
    us* __restrict__ Qhi, us* __restrict__ Qlo,
    us* __restrict__ Khi, us* __restrict__ Klo, us* __restrict__ Vb)
{
  __shared__ unsigned ttile[32 * 193];       // 24,704 B (pitch 193, odd)
  const int t = threadIdx.x;
  const int rb = blockIdx.x;                 // 0..511 (32 rows each; b*N flat)
  const int wid = t >> 6, lane = t & 63;     // wid = col group g, 0..5
  const int l31 = lane & 31, h = lane >> 5;
  const int rbase = rb * 32;
  const float* xrow = x + (size_t)(rbase + l31) * 128;

  f32x16 acc = {};
  #pragma unroll
  for (int ks = 0; ks < 8; ++ks) {           // K = 128 = 8 * 16
    const int d0 = ks * 16 + h * 8;
    const float4 xa = *(const float4*)(xrow + d0);
    const float4 xb = *(const float4*)(xrow + d0 + 4);
    const float xv[8] = {xa.x, xa.y, xa.z, xa.w, xb.x, xb.y, xb.z, xb.w};
    bf16x8 ah, al;
    #pragma unroll
    for (int j = 0; j < 8; ++j) {
      us hi = f2bf(xv[j]);
      ah[j] = (short)hi;
      al[j] = (short)f2bf(xv[j] - bf2f(hi));
    }
    const int wo = ((wid * 8 + ks) * 2 + h) * 256 + l31 * 8;
    bf16x8 bh = *(const bf16x8*)(Wbh + wo);
    bf16x8 bl = *(const bf16x8*)(Wbl + wo);
    acc = mfma(ah, bh, acc);
    acc = mfma(al, bh, acc);
    acc = mfma(ah, bl, acc);
  }

  // pack hi|lo into transpose tile. C layout: row=(r&3)+8*(r>>2)+4h, col=l31
  #pragma unroll
  for (int r = 0; r < 16; ++r) {
    const int rl = (r & 3) + 8 * (r >> 2) + 4 * h;
    float v = acc[r];
    us hi = f2bf(v);
    us lo = f2bf(v - bf2f(hi));
    ttile[rl * 193 + wid * 32 + l31] = (unsigned)hi | ((unsigned)lo << 16);
  }
  __syncthreads();

  // coalesced store phase (local cols: 0..63 Q, 64..127 K, 128..191 V)
  if (t < 64) {              // Q: row = t>>1, 32 cols each
    const int row = t >> 1, cb = (t & 1) * 32;
    const int grow = rbase + row;
    unsigned hw[16], lw[16];
    #pragma unroll
    for (int j = 0; j < 16; ++j) {
      unsigned a = ttile[row * 193 + cb + 2 * j];
      unsigned bv = ttile[row * 193 + cb + 2 * j + 1];
      hw[j] = (a & 0xffffu) | (bv << 16);
      lw[j] = (a >> 16) | (bv & 0xffff0000u);
    }
    #pragma unroll
    for (int j = 0; j < 4; ++j) {
      uint4 hv = {hw[4 * j], hw[4 * j + 1], hw[4 * j + 2], hw[4 * j + 3]};
      uint4 lv = {lw[4 * j], lw[4 * j + 1], lw[4 * j + 2], lw[4 * j + 3]};
      *(uint4*)(Qhi + (size_t)grow * 64 + cb + 8 * j) = hv;
      *(uint4*)(Qlo + (size_t)grow * 64 + cb + 8 * j) = lv;
    }
  } else if (t < 192) {      // K: row = tt>>2, 16 cols each
    const int tt = t - 64;
    const int row = tt >> 2, cs = (tt & 3) * 16;
    const int grow = rbase + row;
    unsigned hw[8], lw[8];
    #pragma unroll
    for (int j = 0; j < 8; ++j) {
      unsigned a = ttile[row * 193 + 64 + cs + 2 * j];
      unsigned bv = ttile[row * 193 + 64 + cs + 2 * j + 1];
      hw[j] = (a & 0xffffu) | (bv << 16);
      lw[j] = (a >> 16) | (bv & 0xffff0000u);
    }
    #pragma unroll
    for (int j = 0; j < 2; ++j) {
      uint4 hv = {hw[4 * j], hw[4 * j + 1], hw[4 * j + 2], hw[4 * j + 3]};
      uint4 lv = {lw[4 * j], lw[4 * j + 1], lw[4 * j + 2], lw[4 * j + 3]};
      *(uint4*)(Khi + (size_t)grow * 64 + cs + 8 * j) = hv;
      *(uint4*)(Klo + (size_t)grow * 64 + cs + 8 * j) = lv;
    }
  } else if (t < 320) {      // V -> Vb B-frag layout (hi plane only)
    const int bb = rbase >> 12;
    const int nb = rbase & 4095;
    #pragma unroll
    for (int i2 = 0; i2 < 2; ++i2) {
      const int c = (t - 192) + 128 * i2;    // 0..255
      const int e = c >> 2, nc = c & 3;      // e 0..63, n-chunk 0..3
      unsigned p[4];
      #pragma unroll
      for (int j = 0; j < 4; ++j) {
        unsigned a = ttile[(nc * 8 + 2 * j) * 193 + 128 + e];
        unsigned bv = ttile[(nc * 8 + 2 * j + 1) * 193 + 128 + e];
        p[j] = (a & 0xffffu) | (bv << 16);
      }
      uint4 pv = {p[0], p[1], p[2], p[3]};
      const int n0 = nb + nc * 8;
      const int kt = n0 >> 6, sub = n0 & 63;
      const int ks = sub >> 4, hh = (sub >> 3) & 1;
      const int dt = e >> 5, lv = e & 31;
      *(uint4*)(Vb + (size_t)bb * 262144 +
                ((((kt * 4 + ks) * 2 + hh) * 2 + dt) * 256 + lv * 8)) = pv;
    }
  }
}

// ---------------------------------------------------------------------------
// Kernel 2: flash attention + fused split-K merge. 1024 blocks x 256 thr
// (4 waves of 32 q). K hi/lo AND V double-buffered via async global_load_lds;
// one barrier per iter; near-one-hot tile skip; v_perm truncating packs.
// ---------------------------------------------------------------------------
__global__ __launch_bounds__(256, 3) void attn_kernel(
    const us* __restrict__ Qhi, const us* __restrict__ Qlo,
    const us* __restrict__ Khi, const us* __restrict__ Klo,
    const us* __restrict__ Vb,
    us* __restrict__ Opart, float* __restrict__ Mpart,
    float* __restrict__ Lpart, float* __restrict__ out, int* __restrict__ cnt)
{
  __shared__ union {
    struct {
      us k[2][2][4096];    // K tiles [buf][hi/lo]: 32,768 B
      us v[2][4096];       // V tiles [buf]: 16,384 B (B-frag order)
    } tl;
    float fb[4][2112];     // epilogue bounce, 33,792 B
  } sm;
  __shared__ float alds[4][32];

  // XCD-aware map: XCD x serves batch x>>1
  const int bx = blockIdx.x;
  const int xc = bx & 7, b = xc >> 1;
  const int idx = ((bx >> 3) << 1) | (xc & 1);      // 0..255
  const int seg = idx & (NSEG - 1), qg = idx >> 3;  // seg 0..7, qg 0..31
  const int t = threadIdx.x;
  const int wid = t >> 6, lane = t & 63;
  const int l31 = lane & 31, h = lane >> 5;
  const int q0 = qg * 128 + wid * 32;               // wave's first q
  const int u = (b * 4096 + q0) >> 5;               // global 32q unit, 0..511
  const size_t pb = (size_t)u * NSEG + seg;

  // persistent Q B-frags: n=l31, k=16ks+8h+j
  bf16x8 qh[4], ql[4];
  {
    const size_t rg = (size_t)(b * 4096 + q0 + l31) * 64;
    #pragma unroll
    for (int ks = 0; ks < 4; ++ks) {
      qh[ks] = *(const bf16x8*)(Qhi + rg + ks * 16 + h * 8);
      ql[ks] = *(const bf16x8*)(Qlo + rg + ks * 16 + h * 8);
    }
  }
  const size_t kbase = (size_t)b * 262144;
  const size_t vbb = (size_t)b * 262144;

  // K staging map (XOR swizzle): thread t -> rows (t>>3, +32), chunk t&7
  const int row0 = t >> 3, slot = t & 7;
  const int gcol = (slot ^ (row0 & 7)) * 8;
  const int wb = 512 * wid;          // K: wave base (us)
  const int vw0 = (wid * 2) * 512;   // V: wave copies 2 x 1KB chunks
  const int vw1 = (wid * 2 + 1) * 512;

  // prologue: tile 0 -> buffer 0 (async DMA)
  {
    const int k0 = seg * 512;
    gld16(Khi + kbase + (size_t)(k0 + row0) * 64 + gcol, &sm.tl.k[0][0][wb]);
    gld16(Khi + kbase + (size_t)(k0 + row0 + 32) * 64 + gcol, &sm.tl.k[0][0][wb + 2048]);
    gld16(Klo + kbase + (size_t)(k0 + row0) * 64 + gcol, &sm.tl.k[0][1][wb]);
    gld16(Klo + kbase + (size_t)(k0 + row0 + 32) * 64 + gcol, &sm.tl.k[0][1][wb + 2048]);
    const size_t vt = vbb + (size_t)(seg * ITERS) * 4096;
    gld16(Vb + vt + vw0 + lane * 8, &sm.tl.v[0][vw0]);
    gld16(Vb + vt + vw1 + lane * 8, &sm.tl.v[0][vw1]);
  }
  __syncthreads();

  f32x16 o[2] = {};
  float mrun = -__builtin_inff();
  float lrun = 0.f;

  for (int it = 0; it < ITERS; ++it) {
    const int cur = it & 1, nxt = cur ^ 1;
    const int KT = seg * ITERS + it;            // global 64-key tile id

    // async prefetch next K+V tiles (drained by the iter-end barrier)
    if (it + 1 < ITERS) {
      const int nk = (KT + 1) * 64;
      gld16(Khi + kbase + (size_t)(nk + row0) * 64 + gcol, &sm.tl.k[nxt][0][wb]);
      gld16(Khi + kbase + (size_t)(nk + row0 + 32) * 64 + gcol, &sm.tl.k[nxt][0][wb + 2048]);
      gld16(Klo + kbase + (size_t)(nk + row0) * 64 + gcol, &sm.tl.k[nxt][1][wb]);
      gld16(Klo + kbase + (size_t)(nk + row0 + 32) * 64 + gcol, &sm.tl.k[nxt][1][wb + 2048]);
      const size_t vt = vbb + (size_t)(KT + 1) * 4096;
      gld16(Vb + vt + vw0 + lane * 8, &sm.tl.v[nxt][vw0]);
      gld16(Vb + vt + vw1 + lane * 8, &sm.tl.v[nxt][vw1]);
    }

    // S^T = K_tile · Q^T (3-pass hi/lo): s[m] C-layout rows=keys, cols=q
    f32x16 s[2] = {};
    #pragma unroll
    for (int m = 0; m < 2; ++m) {
      const int krow = 32 * m + l31;
      #pragma unroll
      for (int ks = 0; ks < 4; ++ks) {
        const int off = krow * 64 + (((2 * ks + h) ^ (l31 & 7)) * 8);
        bf16x8 ah = *(const bf16x8*)(&sm.tl.k[cur][0][off]);
        bf16x8 al = *(const bf16x8*)(&sm.tl.k[cur][1][off]);
        s[m] = mfma(ah, qh[ks], s[m]);
        s[m] = mfma(al, qh[ks], s[m]);
        s[m] = mfma(ah, ql[ks], s[m]);
      }
    }

    // tile max (lane owns q=l31; partner xor-32 has the other 32 keys)
    float vm = -__builtin_inff();
    #pragma unroll
    for (int r = 0; r < 16; ++r)
      vm = fmaxf(vm, fmaxf(s[0][r], s[1][r]));
    vm = fmaxf(vm, __shfl_xor(vm, 32));

    // near-one-hot skip: tile contributes < 64*2^-24 of lrun -> drop it
    if (!__all(vm <= mrun - 24.f)) {
      const float mnew = fmaxf(mrun, vm);
      const float alpha = EXP2(mrun - mnew);
      float sum = 0.f;
      unsigned pp[2][8];
      #pragma unroll
      for (int m = 0; m < 2; ++m) {
        #pragma unroll
        for (int p = 0; p < 8; ++p) {
          const float p0 = EXP2(s[m][2 * p] - mnew);
          const float p1 = EXP2(s[m][2 * p + 1] - mnew);
          sum += p0 + p1;
          pp[m][p] = pk2t(p0, p1);              // one v_perm per pair
        }
      }
      sum += __shfl_xor(sum, 32);
      lrun = lrun * alpha + sum;
      mrun = mnew;

      // rescale O (skip when all-ones; alds broadcast to C-layout rows)
      if (__any(alpha != 1.f)) {
        if (!h) alds[wid][l31] = alpha;
        #pragma unroll
        for (int g = 0; g < 4; ++g) {
          const float4 af4 = *(const float4*)(&alds[wid][8 * g + 4 * h]);
          #pragma unroll
          for (int rr = 0; rr < 4; ++rr) {
            const int r = 4 * g + rr;
            const float a = (rr == 0) ? af4.x : (rr == 1) ? af4.y
                           : (rr == 2) ? af4.z : af4.w;
            o[0][r] *= a;
            o[1][r] *= a;
          }
        }
      }

      // PV: P A-frags via shfl_xor(32) pair exchange; V B-frags from LDS.
      #pragma unroll
      for (int ks = 0; ks < 4; ++ks) {
        const int m = ks >> 1, base = 4 * (ks & 1);
        const unsigned x0 = pp[m][base + 0], x1 = pp[m][base + 1];
        const unsigned x2 = pp[m][base + 2], x3 = pp[m][base + 3];
        const unsigned sA = h ? x0 : x2;
        const unsigned sB = h ? x1 : x3;
        const unsigned rA = (unsigned)__shfl_xor((int)sA, 32);
        const unsigned rB = (unsigned)__shfl_xor((int)sB, 32);
        u32x4 wv;
        wv.x = h ? rA : x0;
        wv.y = h ? rB : x1;
        wv.z = h ? x2 : rA;
        wv.w = h ? x3 : rB;
        const bf16x8 af = __builtin_bit_cast(bf16x8, wv);
        const int vo = ((2 * ks + h) * 2) * 256 + l31 * 8;
        const bf16x8 vf0 = *(const bf16x8*)(&sm.tl.v[cur][vo]);
        const bf16x8 vf1 = *(const bf16x8*)(&sm.tl.v[cur][vo + 256]);
        o[0] = mfma(af, vf0, o[0]);
        o[1] = mfma(af, vf1, o[1]);
      }
    }

    __syncthreads();  // cur reads done; async nxt staging complete
  }

  // epilogue: O -> bf16 Opart via per-wave LDS bounce, dwordx4 stores.
  float* fb = sm.fb[wid];
  #pragma unroll
  for (int dt = 0; dt < 2; ++dt) {
    #pragma unroll
    for (int r = 0; r < 16; ++r) {
      const int qrow = (r & 3) + 8 * (r >> 2) + 4 * h;  // 0..31
      fb[qrow * 66 + l31 + 32 * dt] = o[dt][r];
    }
  }
  #pragma unroll
  for (int jj = 0; jj < 4; ++jj) {
    const int chunk = lane + 64 * jj;           // 0..255
    const int rw = chunk >> 3, part = chunk & 7;
    const float* src = &fb[rw * 66 + part * 8];
    float2 a0 = *(const float2*)(src + 0);
    float2 a1 = *(const float2*)(src + 2);
    float2 a2 = *(const float2*)(src + 4);
    float2 a3 = *(const float2*)(src + 6);
    uint4 pkv;
    pkv.x = pk2t(a0.x, a0.y);
    pkv.y = pk2t(a1.x, a1.y);
    pkv.z = pk2t(a2.x, a2.y);
    pkv.w = pk2t(a3.x, a3.y);
    *(uint4*)(Opart + pb * 2048 + (size_t)rw * 64 + part * 8) = pkv;
  }
  if (!h) {
    Mpart[pb * 32 + l31] = mrun;
    Lpart[pb * 32 + l31] = lrun;
  }

  // ---- fused split-K reduction: 8th arriving seg-wave merges unit u ----
  __threadfence();                              // release our partials
  int old = 0;
  if (lane == 0) old = atomicAdd(&cnt[u], 1);   // device-scope
  old = __shfl(old, 0);
  if (old == NSEG - 1) {
    __threadfence();                            // acquire others' partials
    const int q = lane >> 1, hf = lane & 1;     // lane -> (q, d-half)
    const size_t ub = (size_t)u * NSEG;
    float mv[NSEG];
    float M = -__builtin_inff();
    #pragma unroll
    for (int s2 = 0; s2 < NSEG; ++s2) {
      mv[s2] = Mpart[(ub + s2) * 32 + q];
      M = fmaxf(M, mv[s2]);
    }
    float den = 0.f, acc[32] = {};
    #pragma unroll
    for (int s2 = 0; s2 < NSEG; ++s2) {
      const float wgt = EXP2(mv[s2] - M);
      den += wgt * Lpart[(ub + s2) * 32 + q];
      const us* op = Opart + (ub + s2) * 2048 + q * 64 + hf * 32;
      #pragma unroll
      for (int j = 0; j < 4; ++j) {
        const uint4 r = *(const uint4*)(op + j * 8);
        const unsigned rw[4] = {r.x, r.y, r.z, r.w};
        #pragma unroll
        for (int k2 = 0; k2 < 4; ++k2) {
          acc[j * 8 + 2 * k2]     += wgt * bf2f((us)(rw[k2] & 0xffffu));
          acc[j * 8 + 2 * k2 + 1] += wgt * bf2f((us)(rw[k2] >> 16));
        }
      }
    }
    const float inv = 1.f / den;
    float* dst = out + (size_t)(u * 32 + q) * 64 + hf * 32;
    #pragma unroll
    for (int j = 0; j < 8; ++j) {
      float4 r4 = {acc[4 * j] * inv, acc[4 * j + 1] * inv,
                   acc[4 * j + 2] * inv, acc[4 * j + 3] * inv};
      *(float4*)(dst + 4 * j) = r4;
    }
  }
}

// ---------------------------------------------------------------------------
extern "C" void kernel_launch(void* const* d_in, const int* in_sizes, int n_in,
                              void* d_out, int out_size, void* d_ws,
                              size_t ws_size, hipStream_t stream)
{
  const float* x = (const float*)d_in[0];
  const float* w = (const float*)d_in[1];
  float* out = (float*)d_out;
  char* ws = (char*)d_ws;

  const size_t T = 2097152;  // bytes per bf16 [4,4096,64] tensor
  us* Qhi = (us*)(ws + 0 * T);
  us* Qlo = (us*)(ws + 1 * T);
  us* Khi = (us*)(ws + 2 * T);
  us* Klo = (us*)(ws + 3 * T);
  us* Vb  = (us*)(ws + 4 * T);
  us* Wbh = (us*)(ws + 5 * T);                    // 49,152 B
  us* Wbl = (us*)(ws + 5 * T + 49152);            // 49,152 B
  char* pbase = ws + 5 * T + 98304;
  us* Opart = (us*)pbase;                                    // 16,777,216 B
  float* Mpart = (float*)(pbase + 16777216);                 //    524,288 B
  float* Lpart = (float*)(pbase + 16777216 + 524288);        //    524,288 B
  int* cnt = (int*)(pbase + 16777216 + 1048576);             //      2,048 B
  // total workspace use: ~28.4 MiB

  hipLaunchKernelGGL(wprep_kernel, dim3(96), dim3(256), 0, stream,
                     w, Wbh, Wbl, cnt);
  hipLaunchKernelGGL(qkv_kernel, dim3(512), dim3(384), 0, stream,
                     x, Wbh, Wbl, Qhi, Qlo, Khi, Klo, Vb);
  hipLaunchKernelGGL(attn_kernel, dim3(1024), dim3(256), 0, stream,
                     Qhi, Qlo, Khi, Klo, Vb, Opart, Mpart, Lpart, out, cnt);
}

// Round 8
// 140.857 us; speedup vs baseline: 2.1573x; 2.1573x over previous
//
#include <hip/hip_runtime.h>

// ---------------------------------------------------------------------------
// Self-attention: out = softmax((xWq)(xWk)^T / sqrt(64)) (xWv)
// B=4, N=4096, Din=128, Dout=64.
//   k0 wprep : W -> hi/lo bf16 planes in MFMA B-frag order (Q-scale folded).
//   k1 qkv   : x@W, wave = 32 rows x 32 cols (3-pass bf16 MFMA), 512 blocks
//              x 384 thr (6 waves). Epilogue LDS transpose, coalesced stores.
//   k2 attn  : flash attention, 32-q waves, nseg=8. K hi/lo AND V double-
//              buffered via async global_load_lds; v_perm truncating packs;
//              near-one-hot tile skip; rescale tolerance 0.5 (alpha==1 path);
//              P C->A via shfl_xor(32). NO device-scope fences (round-7
//              lesson: per-block __threadfence = L2 invalidation storm).
//   k3 merge : combine 8 segment partials (bf16 O partials), separate dispatch.
// ---------------------------------------------------------------------------

typedef __attribute__((ext_vector_type(8))) short bf16x8;
typedef __attribute__((ext_vector_type(16))) float f32x16;
typedef __attribute__((ext_vector_type(4))) unsigned u32x4;
typedef unsigned short us;

__device__ __forceinline__ us f2bf(float f) {               // RTNE fp32->bf16
  unsigned u = __builtin_bit_cast(unsigned, f);
  u += 0x7FFFu + ((u >> 16) & 1u);
  return (us)(u >> 16);
}
__device__ __forceinline__ float bf2f(us h) {
  unsigned u = ((unsigned)h) << 16;
  return __builtin_bit_cast(float, u);
}
__device__ __forceinline__ f32x16 mfma(bf16x8 a, bf16x8 b, f32x16 c) {
  return __builtin_amdgcn_mfma_f32_32x32x16_bf16(a, b, c, 0, 0, 0);
}
// truncating pack: low16 = bf16_trunc(a), high16 = bf16_trunc(b). ONE v_perm.
__device__ __forceinline__ unsigned pk2t(float a, float b) {
  return __builtin_amdgcn_perm(__builtin_bit_cast(unsigned, b),
                               __builtin_bit_cast(unsigned, a), 0x07060302u);
}
#define EXP2(x) __builtin_amdgcn_exp2f(x)

// async 16B global->LDS DMA: lane i lands at ldsbase + 16*i
__device__ __forceinline__ void gld16(const us* g, us* l) {
  __builtin_amdgcn_global_load_lds(
      (__attribute__((address_space(1))) const unsigned int*)g,
      (__attribute__((address_space(3))) unsigned int*)l, 16, 0, 0);
}

#define NSEG 8
#define ITERS 8

// ---------------------------------------------------------------------------
// Kernel 0: W prep. w[3][128][64] fp32 -> Wbh/Wbl bf16 hi/lo, B-frag order:
// idx = ((g*8+ks)*2+h)*256 + (e&31)*8 + j; g=(p*64+e)>>5. p==0 pre-scaled
// by 0.125*log2(e).
// ---------------------------------------------------------------------------
__global__ __launch_bounds__(256, 1) void wprep_kernel(
    const float* __restrict__ w, us* __restrict__ Wbh, us* __restrict__ Wbl)
{
  const int i = blockIdx.x * 256 + threadIdx.x;
  if (i >= 24576) return;
  const int p = i >> 13, d = (i & 8191) >> 6, e = i & 63;
  float v = w[i];
  if (p == 0) v *= 0.18033688011112042f;
  const us hi = f2bf(v);
  const us lo = f2bf(v - bf2f(hi));
  const int g = (p * 64 + e) >> 5, ks = d >> 4, hh = (d >> 3) & 1, j = d & 7;
  const int o = ((g * 8 + ks) * 2 + hh) * 256 + (e & 31) * 8 + j;
  Wbh[o] = hi;
  Wbl[o] = lo;
}

// ---------------------------------------------------------------------------
// Kernel 1: QKV projection. 512 blocks x 384 thr (6 waves). Block = 32 rows
// x 192 cols; wave wid covers col group wid*32 (= Wb 'g' index).
// ---------------------------------------------------------------------------
__global__ __launch_bounds__(384, 1) void qkv_kernel(
    const float* __restrict__ x,
    const us* __restrict__ Wbh, const us* __restrict__ Wbl,
    us* __restrict__ Qhi, us* __restrict__ Qlo,
    us* __restrict__ Khi, us* __restrict__ Klo, us* __restrict__ Vb)
{
  __shared__ unsigned ttile[32 * 193];       // 24,704 B
  const int t = threadIdx.x;
  const int rb = blockIdx.x;                 // 0..511 (32 rows each)
  const int wid = t >> 6, lane = t & 63;     // wid = col group g, 0..5
  const int l31 = lane & 31, h = lane >> 5;
  const int rbase = rb * 32;
  const float* xrow = x + (size_t)(rbase + l31) * 128;

  f32x16 acc = {};
  #pragma unroll
  for (int ks = 0; ks < 8; ++ks) {           // K = 128 = 8 * 16
    const int d0 = ks * 16 + h * 8;
    const float4 xa = *(const float4*)(xrow + d0);
    const float4 xb = *(const float4*)(xrow + d0 + 4);
    const float xv[8] = {xa.x, xa.y, xa.z, xa.w, xb.x, xb.y, xb.z, xb.w};
    bf16x8 ah, al;
    #pragma unroll
    for (int j = 0; j < 8; ++j) {
      us hi = f2bf(xv[j]);
      ah[j] = (short)hi;
      al[j] = (short)f2bf(xv[j] - bf2f(hi));
    }
    const int wo = ((wid * 8 + ks) * 2 + h) * 256 + l31 * 8;
    bf16x8 bh = *(const bf16x8*)(Wbh + wo);
    bf16x8 bl = *(const bf16x8*)(Wbl + wo);
    acc = mfma(ah, bh, acc);
    acc = mfma(al, bh, acc);
    acc = mfma(ah, bl, acc);
  }

  // pack hi|lo into transpose tile. C layout: row=(r&3)+8*(r>>2)+4h, col=l31
  #pragma unroll
  for (int r = 0; r < 16; ++r) {
    const int rl = (r & 3) + 8 * (r >> 2) + 4 * h;
    float v = acc[r];
    us hi = f2bf(v);
    us lo = f2bf(v - bf2f(hi));
    ttile[rl * 193 + wid * 32 + l31] = (unsigned)hi | ((unsigned)lo << 16);
  }
  __syncthreads();

  // coalesced store phase (local cols: 0..63 Q, 64..127 K, 128..191 V)
  if (t < 64) {              // Q: row = t>>1, 32 cols each
    const int row = t >> 1, cb = (t & 1) * 32;
    const int grow = rbase + row;
    unsigned hw[16], lw[16];
    #pragma unroll
    for (int j = 0; j < 16; ++j) {
      unsigned a = ttile[row * 193 + cb + 2 * j];
      unsigned bv = ttile[row * 193 + cb + 2 * j + 1];
      hw[j] = (a & 0xffffu) | (bv << 16);
      lw[j] = (a >> 16) | (bv & 0xffff0000u);
    }
    #pragma unroll
    for (int j = 0; j < 4; ++j) {
      uint4 hv = {hw[4 * j], hw[4 * j + 1], hw[4 * j + 2], hw[4 * j + 3]};
      uint4 lv = {lw[4 * j], lw[4 * j + 1], lw[4 * j + 2], lw[4 * j + 3]};
      *(uint4*)(Qhi + (size_t)grow * 64 + cb + 8 * j) = hv;
      *(uint4*)(Qlo + (size_t)grow * 64 + cb + 8 * j) = lv;
    }
  } else if (t < 192) {      // K: row = tt>>2, 16 cols each
    const int tt = t - 64;
    const int row = tt >> 2, cs = (tt & 3) * 16;
    const int grow = rbase + row;
    unsigned hw[8], lw[8];
    #pragma unroll
    for (int j = 0; j < 8; ++j) {
      unsigned a = ttile[row * 193 + 64 + cs + 2 * j];
      unsigned bv = ttile[row * 193 + 64 + cs + 2 * j + 1];
      hw[j] = (a & 0xffffu) | (bv << 16);
      lw[j] = (a >> 16) | (bv & 0xffff0000u);
    }
    #pragma unroll
    for (int j = 0; j < 2; ++j) {
      uint4 hv = {hw[4 * j], hw[4 * j + 1], hw[4 * j + 2], hw[4 * j + 3]};
      uint4 lv = {lw[4 * j], lw[4 * j + 1], lw[4 * j + 2], lw[4 * j + 3]};
      *(uint4*)(Khi + (size_t)grow * 64 + cs + 8 * j) = hv;
      *(uint4*)(Klo + (size_t)grow * 64 + cs + 8 * j) = lv;
    }
  } else if (t < 320) {      // V -> Vb B-frag layout (hi plane only)
    const int bb = rbase >> 12;
    const int nb = rbase & 4095;
    #pragma unroll
    for (int i2 = 0; i2 < 2; ++i2) {
      const int c = (t - 192) + 128 * i2;    // 0..255
      const int e = c >> 2, nc = c & 3;      // e 0..63, n-chunk 0..3
      unsigned p[4];
      #pragma unroll
      for (int j = 0; j < 4; ++j) {
        unsigned a = ttile[(nc * 8 + 2 * j) * 193 + 128 + e];
        unsigned bv = ttile[(nc * 8 + 2 * j + 1) * 193 + 128 + e];
        p[j] = (a & 0xffffu) | (bv << 16);
      }
      uint4 pv = {p[0], p[1], p[2], p[3]};
      const int n0 = nb + nc * 8;
      const int kt = n0 >> 6, sub = n0 & 63;
      const int ks = sub >> 4, hh = (sub >> 3) & 1;
      const int dt = e >> 5, lv = e & 31;
      *(uint4*)(Vb + (size_t)bb * 262144 +
                ((((kt * 4 + ks) * 2 + hh) * 2 + dt) * 256 + lv * 8)) = pv;
    }
  }
}

// ---------------------------------------------------------------------------
// Kernel 2: flash attention partials. 1024 blocks x 256 thr (4 waves of
// 32 q). K hi/lo AND V double-buffered via async global_load_lds; one
// barrier per iter; near-one-hot skip; rescale tolerance; v_perm packs.
// ---------------------------------------------------------------------------
__global__ __launch_bounds__(256, 3) void attn_kernel(
    const us* __restrict__ Qhi, const us* __restrict__ Qlo,
    const us* __restrict__ Khi, const us* __restrict__ Klo,
    const us* __restrict__ Vb,
    us* __restrict__ Opart, float* __restrict__ Mpart,
    float* __restrict__ Lpart)
{
  __shared__ union {
    struct {
      us k[2][2][4096];    // K tiles [buf][hi/lo]: 32,768 B
      us v[2][4096];       // V tiles [buf]: 16,384 B (B-frag order)
    } tl;
    float fb[4][2112];     // epilogue bounce, 33,792 B
  } sm;
  __shared__ float alds[4][32];

  // XCD-aware map: XCD x serves batch x>>1
  const int bx = blockIdx.x;
  const int xc = bx & 7, b = xc >> 1;
  const int idx = ((bx >> 3) << 1) | (xc & 1);      // 0..255
  const int seg = idx & (NSEG - 1), qg = idx >> 3;  // seg 0..7, qg 0..31
  const int t = threadIdx.x;
  const int wid = t >> 6, lane = t & 63;
  const int l31 = lane & 31, h = lane >> 5;
  const int q0 = qg * 128 + wid * 32;               // wave's first q
  const int u = (b * 4096 + q0) >> 5;               // global 32q unit
  const size_t pb = (size_t)u * NSEG + seg;

  // persistent Q B-frags: n=l31, k=16ks+8h+j
  bf16x8 qh[4], ql[4];
  {
    const size_t rg = (size_t)(b * 4096 + q0 + l31) * 64;
    #pragma unroll
    for (int ks = 0; ks < 4; ++ks) {
      qh[ks] = *(const bf16x8*)(Qhi + rg + ks * 16 + h * 8);
      ql[ks] = *(const bf16x8*)(Qlo + rg + ks * 16 + h * 8);
    }
  }
  const size_t kbase = (size_t)b * 262144;
  const size_t vbb = (size_t)b * 262144;

  // K staging map (XOR swizzle): thread t -> rows (t>>3, +32), chunk t&7
  const int row0 = t >> 3, slot = t & 7;
  const int gcol = (slot ^ (row0 & 7)) * 8;
  const int wb = 512 * wid;          // K: wave base (us)
  const int vw0 = (wid * 2) * 512;   // V: wave copies 2 x 1KB chunks
  const int vw1 = (wid * 2 + 1) * 512;

  // prologue: tile 0 -> buffer 0 (async DMA)
  {
    const int k0 = seg * 512;
    gld16(Khi + kbase + (size_t)(k0 + row0) * 64 + gcol, &sm.tl.k[0][0][wb]);
    gld16(Khi + kbase + (size_t)(k0 + row0 + 32) * 64 + gcol, &sm.tl.k[0][0][wb + 2048]);
    gld16(Klo + kbase + (size_t)(k0 + row0) * 64 + gcol, &sm.tl.k[0][1][wb]);
    gld16(Klo + kbase + (size_t)(k0 + row0 + 32) * 64 + gcol, &sm.tl.k[0][1][wb + 2048]);
    const size_t vt = vbb + (size_t)(seg * ITERS) * 4096;
    gld16(Vb + vt + vw0 + lane * 8, &sm.tl.v[0][vw0]);
    gld16(Vb + vt + vw1 + lane * 8, &sm.tl.v[0][vw1]);
  }
  __syncthreads();

  f32x16 o[2] = {};
  float mrun = -__builtin_inff();
  float lrun = 0.f;

  for (int it = 0; it < ITERS; ++it) {
    const int cur = it & 1, nxt = cur ^ 1;
    const int KT = seg * ITERS + it;            // global 64-key tile id

    // async prefetch next K+V tiles (drained by the iter-end barrier)
    if (it + 1 < ITERS) {
      const int nk = (KT + 1) * 64;
      gld16(Khi + kbase + (size_t)(nk + row0) * 64 + gcol, &sm.tl.k[nxt][0][wb]);
      gld16(Khi + kbase + (size_t)(nk + row0 + 32) * 64 + gcol, &sm.tl.k[nxt][0][wb + 2048]);
      gld16(Klo + kbase + (size_t)(nk + row0) * 64 + gcol, &sm.tl.k[nxt][1][wb]);
      gld16(Klo + kbase + (size_t)(nk + row0 + 32) * 64 + gcol, &sm.tl.k[nxt][1][wb + 2048]);
      const size_t vt = vbb + (size_t)(KT + 1) * 4096;
      gld16(Vb + vt + vw0 + lane * 8, &sm.tl.v[nxt][vw0]);
      gld16(Vb + vt + vw1 + lane * 8, &sm.tl.v[nxt][vw1]);
    }

    // S^T = K_tile · Q^T (3-pass hi/lo): s[m] C-layout rows=keys, cols=q
    f32x16 s[2] = {};
    #pragma unroll
    for (int m = 0; m < 2; ++m) {
      const int krow = 32 * m + l31;
      #pragma unroll
      for (int ks = 0; ks < 4; ++ks) {
        const int off = krow * 64 + (((2 * ks + h) ^ (l31 & 7)) * 8);
        bf16x8 ah = *(const bf16x8*)(&sm.tl.k[cur][0][off]);
        bf16x8 al = *(const bf16x8*)(&sm.tl.k[cur][1][off]);
        s[m] = mfma(ah, qh[ks], s[m]);
        s[m] = mfma(al, qh[ks], s[m]);
        s[m] = mfma(ah, ql[ks], s[m]);
      }
    }

    // tile max (lane owns q=l31; partner xor-32 has the other 32 keys)
    float vm = -__builtin_inff();
    #pragma unroll
    for (int r = 0; r < 16; ++r)
      vm = fmaxf(vm, fmaxf(s[0][r], s[1][r]));
    vm = fmaxf(vm, __shfl_xor(vm, 32));

    // near-one-hot skip: tile contributes < 2^-24 of lrun -> drop it
    if (!__all(vm <= mrun - 24.f)) {
      // rescale tolerance: only adopt a higher max if it rose by > 0.5
      // (P entries may reach 2^0.5; keeps alpha == 1 on most iters)
      const float mnew = (vm > mrun + 0.5f) ? vm : mrun;
      const float alpha = EXP2(mrun - mnew);    // 1.0 when mnew==mrun
      float sum = 0.f;
      unsigned pp[2][8];
      #pragma unroll
      for (int m = 0; m < 2; ++m) {
        #pragma unroll
        for (int p = 0; p < 8; ++p) {
          const float p0 = EXP2(s[m][2 * p] - mnew);
          const float p1 = EXP2(s[m][2 * p + 1] - mnew);
          sum += p0 + p1;
          pp[m][p] = pk2t(p0, p1);              // one v_perm per pair
        }
      }
      sum += __shfl_xor(sum, 32);
      lrun = lrun * alpha + sum;
      mrun = mnew;

      // rescale O (rare now; alds broadcast to C-layout rows)
      if (__any(alpha != 1.f)) {
        if (!h) alds[wid][l31] = alpha;
        #pragma unroll
        for (int g = 0; g < 4; ++g) {
          const float4 af4 = *(const float4*)(&alds[wid][8 * g + 4 * h]);
          #pragma unroll
          for (int rr = 0; rr < 4; ++rr) {
            const int r = 4 * g + rr;
            const float a = (rr == 0) ? af4.x : (rr == 1) ? af4.y
                           : (rr == 2) ? af4.z : af4.w;
            o[0][r] *= a;
            o[1][r] *= a;
          }
        }
      }

      // PV: P A-frags via shfl_xor(32) pair exchange; V B-frags from LDS.
      #pragma unroll
      for (int ks = 0; ks < 4; ++ks) {
        const int m = ks >> 1, base = 4 * (ks & 1);
        const unsigned x0 = pp[m][base + 0], x1 = pp[m][base + 1];
        const unsigned x2 = pp[m][base + 2], x3 = pp[m][base + 3];
        const unsigned sA = h ? x0 : x2;
        const unsigned sB = h ? x1 : x3;
        const unsigned rA = (unsigned)__shfl_xor((int)sA, 32);
        const unsigned rB = (unsigned)__shfl_xor((int)sB, 32);
        u32x4 wv;
        wv.x = h ? rA : x0;
        wv.y = h ? rB : x1;
        wv.z = h ? x2 : rA;
        wv.w = h ? x3 : rB;
        const bf16x8 af = __builtin_bit_cast(bf16x8, wv);
        const int vo = ((2 * ks + h) * 2) * 256 + l31 * 8;
        const bf16x8 vf0 = *(const bf16x8*)(&sm.tl.v[cur][vo]);
        const bf16x8 vf1 = *(const bf16x8*)(&sm.tl.v[cur][vo + 256]);
        o[0] = mfma(af, vf0, o[0]);
        o[1] = mfma(af, vf1, o[1]);
      }
    }

    __syncthreads();  // cur reads done; async nxt staging complete
  }

  // epilogue: O -> bf16 Opart via per-wave LDS bounce, dwordx4 stores.
  float* fb = sm.fb[wid];
  #pragma unroll
  for (int dt = 0; dt < 2; ++dt) {
    #pragma unroll
    for (int r = 0; r < 16; ++r) {
      const int qrow = (r & 3) + 8 * (r >> 2) + 4 * h;  // 0..31
      fb[qrow * 66 + l31 + 32 * dt] = o[dt][r];
    }
  }
  #pragma unroll
  for (int jj = 0; jj < 4; ++jj) {
    const int chunk = lane + 64 * jj;           // 0..255
    const int rw = chunk >> 3, part = chunk & 7;
    const float* src = &fb[rw * 66 + part * 8];
    float2 a0 = *(const float2*)(src + 0);
    float2 a1 = *(const float2*)(src + 2);
    float2 a2 = *(const float2*)(src + 4);
    float2 a3 = *(const float2*)(src + 6);
    uint4 pkv;
    pkv.x = pk2t(a0.x, a0.y);
    pkv.y = pk2t(a1.x, a1.y);
    pkv.z = pk2t(a2.x, a2.y);
    pkv.w = pk2t(a3.x, a3.y);
    *(uint4*)(Opart + pb * 2048 + (size_t)rw * 64 + part * 8) = pkv;
  }
  if (!h) {
    Mpart[pb * 32 + l31] = mrun;
    Lpart[pb * 32 + l31] = lrun;
  }
}

// ---------------------------------------------------------------------------
// Kernel 3: merge 8 key-segment partials (bf16). 131072 thr, 8 d each.
// ---------------------------------------------------------------------------
__global__ __launch_bounds__(256, 1) void merge_kernel(
    const us* __restrict__ Opart, const float* __restrict__ Mpart,
    const float* __restrict__ Lpart, float* __restrict__ out)
{
  const int tg = blockIdx.x * 256 + threadIdx.x;
  const int q = tg >> 3, dc = (tg & 7) * 8;
  const int u = q >> 5, ql = q & 31;
  const int base = u * NSEG;
  float M = -__builtin_inff();
  #pragma unroll
  for (int s = 0; s < NSEG; ++s)
    M = fmaxf(M, Mpart[(size_t)(base + s) * 32 + ql]);
  float acc[8] = {};
  float den = 0.f;
  #pragma unroll
  for (int s = 0; s < NSEG; ++s) {
    const float wgt = EXP2(Mpart[(size_t)(base + s) * 32 + ql] - M);
    den += wgt * Lpart[(size_t)(base + s) * 32 + ql];
    const uint4 r = *(const uint4*)(Opart + (size_t)(base + s) * 2048 +
                                    ql * 64 + dc);
    const unsigned rw[4] = {r.x, r.y, r.z, r.w};
    #pragma unroll
    for (int j = 0; j < 4; ++j) {
      acc[2 * j]     += wgt * bf2f((us)(rw[j] & 0xffffu));
      acc[2 * j + 1] += wgt * bf2f((us)(rw[j] >> 16));
    }
  }
  const float inv = 1.f / den;
  float4 r0 = {acc[0] * inv, acc[1] * inv, acc[2] * inv, acc[3] * inv};
  float4 r1 = {acc[4] * inv, acc[5] * inv, acc[6] * inv, acc[7] * inv};
  *(float4*)(out + (size_t)q * 64 + dc) = r0;
  *(float4*)(out + (size_t)q * 64 + dc + 4) = r1;
}

// ---------------------------------------------------------------------------
extern "C" void kernel_launch(void* const* d_in, const int* in_sizes, int n_in,
                              void* d_out, int out_size, void* d_ws,
                              size_t ws_size, hipStream_t stream)
{
  const float* x = (const float*)d_in[0];
  const float* w = (const float*)d_in[1];
  float* out = (float*)d_out;
  char* ws = (char*)d_ws;

  const size_t T = 2097152;  // bytes per bf16 [4,4096,64] tensor
  us* Qhi = (us*)(ws + 0 * T);
  us* Qlo = (us*)(ws + 1 * T);
  us* Khi = (us*)(ws + 2 * T);
  us* Klo = (us*)(ws + 3 * T);
  us* Vb  = (us*)(ws + 4 * T);
  us* Wbh = (us*)(ws + 5 * T);                    // 49,152 B
  us* Wbl = (us*)(ws + 5 * T + 49152);            // 49,152 B
  char* pbase = ws + 5 * T + 98304;
  us* Opart = (us*)pbase;                                    // 16,777,216 B
  float* Mpart = (float*)(pbase + 16777216);                 //    524,288 B
  float* Lpart = (float*)(pbase + 16777216 + 524288);        //    524,288 B
  // total workspace use: ~28.4 MiB

  hipLaunchKernelGGL(wprep_kernel, dim3(96), dim3(256), 0, stream,
                     w, Wbh, Wbl);
  hipLaunchKernelGGL(qkv_kernel, dim3(512), dim3(384), 0, stream,
                     x, Wbh, Wbl, Qhi, Qlo, Khi, Klo, Vb);
  hipLaunchKernelGGL(attn_kernel, dim3(1024), dim3(256), 0, stream,
                     Qhi, Qlo, Khi, Klo, Vb, Opart, Mpart, Lpart);
  hipLaunchKernelGGL(merge_kernel, dim3(512), dim3(256), 0, stream,
                     Opart, Mpart, Lpart, out);
}

// Round 9
// 127.179 us; speedup vs baseline: 2.3894x; 1.1075x over previous
//
#include <hip/hip_runtime.h>

// ---------------------------------------------------------------------------
// Self-attention: out = softmax((xWq)(xWk)^T / sqrt(64)) (xWv)
// B=4, N=4096, Din=128, Dout=64.
//   k0 wprep : W -> hi/lo bf16 planes in MFMA B-frag order (Q-scale folded).
//   k1 qkv   : x@W (3-pass bf16 MFMA). Outputs Qhi/Qlo row-major, K hi/lo in
//              A-FRAG TILE ORDER (Kbh/Kbl), V in B-frag order (Vb).
//   k2 attn  : flash attention, 32-q waves, nseg=8. BARRIER-FREE K-loop:
//              K/V fragments read directly from frag-ordered global layouts
//              (2x512B contiguous per wave-load, L2-hot) — no LDS staging,
//              no DMA, no __syncthreads in the loop. LDS = epilogue only.
//   k3 merge : combine 8 segment partials (bf16 O partials).
// ---------------------------------------------------------------------------

typedef __attribute__((ext_vector_type(8))) short bf16x8;
typedef __attribute__((ext_vector_type(16))) float f32x16;
typedef __attribute__((ext_vector_type(4))) unsigned u32x4;
typedef unsigned short us;

__device__ __forceinline__ us f2bf(float f) {               // RTNE fp32->bf16
  unsigned u = __builtin_bit_cast(unsigned, f);
  u += 0x7FFFu + ((u >> 16) & 1u);
  return (us)(u >> 16);
}
__device__ __forceinline__ float bf2f(us h) {
  unsigned u = ((unsigned)h) << 16;
  return __builtin_bit_cast(float, u);
}
__device__ __forceinline__ f32x16 mfma(bf16x8 a, bf16x8 b, f32x16 c) {
  return __builtin_amdgcn_mfma_f32_32x32x16_bf16(a, b, c, 0, 0, 0);
}
// truncating pack: low16 = bf16_trunc(a), high16 = bf16_trunc(b). ONE v_perm.
__device__ __forceinline__ unsigned pk2t(float a, float b) {
  return __builtin_amdgcn_perm(__builtin_bit_cast(unsigned, b),
                               __builtin_bit_cast(unsigned, a), 0x07060302u);
}
#define EXP2(x) __builtin_amdgcn_exp2f(x)

#define NSEG 8
#define ITERS 8

// ---------------------------------------------------------------------------
// Kernel 0: W prep. w[3][128][64] fp32 -> Wbh/Wbl bf16 hi/lo, B-frag order:
// idx = ((g*8+ks)*2+h)*256 + (e&31)*8 + j; g=(p*64+e)>>5. p==0 pre-scaled
// by 0.125*log2(e).
// ---------------------------------------------------------------------------
__global__ __launch_bounds__(256, 1) void wprep_kernel(
    const float* __restrict__ w, us* __restrict__ Wbh, us* __restrict__ Wbl)
{
  const int i = blockIdx.x * 256 + threadIdx.x;
  if (i >= 24576) return;
  const int p = i >> 13, d = (i & 8191) >> 6, e = i & 63;
  float v = w[i];
  if (p == 0) v *= 0.18033688011112042f;
  const us hi = f2bf(v);
  const us lo = f2bf(v - bf2f(hi));
  const int g = (p * 64 + e) >> 5, ks = d >> 4, hh = (d >> 3) & 1, j = d & 7;
  const int o = ((g * 8 + ks) * 2 + hh) * 256 + (e & 31) * 8 + j;
  Wbh[o] = hi;
  Wbl[o] = lo;
}

// ---------------------------------------------------------------------------
// Kernel 1: QKV projection. 512 blocks x 384 thr (6 waves). Block = 32 rows
// x 192 cols. K stored in A-frag tile order:
//   Kb flat = (kt*16 + ks*4 + 2h + m)*256 + r*8 + j
//   (kt = 64-key tile, m = 32-row half, r = row in half, k = 16ks+8h+j)
// so an attn wave-load (lane = 32h + l31) at base + h*512 + l31*8 is two
// contiguous 512B blocks.
// ---------------------------------------------------------------------------
__global__ __launch_bounds__(384, 1) void qkv_kernel(
    const float* __restrict__ x,
    const us* __restrict__ Wbh, const us* __restrict__ Wbl,
    us* __restrict__ Qhi, us* __restrict__ Qlo,
    us* __restrict__ Kbh, us* __restrict__ Kbl, us* __restrict__ Vb)
{
  __shared__ unsigned ttile[32 * 193];       // 24,704 B
  const int t = threadIdx.x;
  const int rb = blockIdx.x;                 // 0..511 (32 rows each)
  const int wid = t >> 6, lane = t & 63;     // wid = col group g, 0..5
  const int l31 = lane & 31, h = lane >> 5;
  const int rbase = rb * 32;
  const float* xrow = x + (size_t)(rbase + l31) * 128;

  f32x16 acc = {};
  #pragma unroll
  for (int ks = 0; ks < 8; ++ks) {           // K = 128 = 8 * 16
    const int d0 = ks * 16 + h * 8;
    const float4 xa = *(const float4*)(xrow + d0);
    const float4 xb = *(const float4*)(xrow + d0 + 4);
    const float xv[8] = {xa.x, xa.y, xa.z, xa.w, xb.x, xb.y, xb.z, xb.w};
    bf16x8 ah, al;
    #pragma unroll
    for (int j = 0; j < 8; ++j) {
      us hi = f2bf(xv[j]);
      ah[j] = (short)hi;
      al[j] = (short)f2bf(xv[j] - bf2f(hi));
    }
    const int wo = ((wid * 8 + ks) * 2 + h) * 256 + l31 * 8;
    bf16x8 bh = *(const bf16x8*)(Wbh + wo);
    bf16x8 bl = *(const bf16x8*)(Wbl + wo);
    acc = mfma(ah, bh, acc);
    acc = mfma(al, bh, acc);
    acc = mfma(ah, bl, acc);
  }

  // pack hi|lo into transpose tile. C layout: row=(r&3)+8*(r>>2)+4h, col=l31
  #pragma unroll
  for (int r = 0; r < 16; ++r) {
    const int rl = (r & 3) + 8 * (r >> 2) + 4 * h;
    float v = acc[r];
    us hi = f2bf(v);
    us lo = f2bf(v - bf2f(hi));
    ttile[rl * 193 + wid * 32 + l31] = (unsigned)hi | ((unsigned)lo << 16);
  }
  __syncthreads();

  // coalesced store phase (local cols: 0..63 Q, 64..127 K, 128..191 V)
  if (t < 64) {              // Q: row = t>>1, 32 cols each
    const int row = t >> 1, cb = (t & 1) * 32;
    const int grow = rbase + row;
    unsigned hw[16], lw[16];
    #pragma unroll
    for (int j = 0; j < 16; ++j) {
      unsigned a = ttile[row * 193 + cb + 2 * j];
      unsigned bv = ttile[row * 193 + cb + 2 * j + 1];
      hw[j] = (a & 0xffffu) | (bv << 16);
      lw[j] = (a >> 16) | (bv & 0xffff0000u);
    }
    #pragma unroll
    for (int j = 0; j < 4; ++j) {
      uint4 hv = {hw[4 * j], hw[4 * j + 1], hw[4 * j + 2], hw[4 * j + 3]};
      uint4 lv = {lw[4 * j], lw[4 * j + 1], lw[4 * j + 2], lw[4 * j + 3]};
      *(uint4*)(Qhi + (size_t)grow * 64 + cb + 8 * j) = hv;
      *(uint4*)(Qlo + (size_t)grow * 64 + cb + 8 * j) = lv;
    }
  } else if (t < 192) {      // K -> Kbh/Kbl A-frag tile layout
    const int bb = rbase >> 12;
    const int kt = (rbase & 4095) >> 6;
    const int m = (rbase >> 5) & 1;
    const size_t kbb = (size_t)bb * 262144 + (size_t)kt * 4096 + m * 256;
    #pragma unroll
    for (int i2 = 0; i2 < 2; ++i2) {
      const int c = (t - 64) + 128 * i2;     // 0..255
      const int r = c & 31, hh = (c >> 5) & 1, ks = c >> 6;
      unsigned hw[4], lw[4];
      #pragma unroll
      for (int j = 0; j < 4; ++j) {
        unsigned a = ttile[r * 193 + 64 + 16 * ks + 8 * hh + 2 * j];
        unsigned bv = ttile[r * 193 + 64 + 16 * ks + 8 * hh + 2 * j + 1];
        hw[j] = (a & 0xffffu) | (bv << 16);
        lw[j] = (a >> 16) | (bv & 0xffff0000u);
      }
      const size_t off = kbb + (size_t)(ks * 4 + 2 * hh) * 256 + r * 8;
      uint4 hv = {hw[0], hw[1], hw[2], hw[3]};
      uint4 lv = {lw[0], lw[1], lw[2], lw[3]};
      *(uint4*)(Kbh + off) = hv;
      *(uint4*)(Kbl + off) = lv;
    }
  } else if (t < 320) {      // V -> Vb B-frag layout (hi plane only)
    const int bb = rbase >> 12;
    const int nb = rbase & 4095;
    #pragma unroll
    for (int i2 = 0; i2 < 2; ++i2) {
      const int c = (t - 192) + 128 * i2;    // 0..255
      const int e = c >> 2, nc = c & 3;      // e 0..63, n-chunk 0..3
      unsigned p[4];
      #pragma unroll
      for (int j = 0; j < 4; ++j) {
        unsigned a = ttile[(nc * 8 + 2 * j) * 193 + 128 + e];
        unsigned bv = ttile[(nc * 8 + 2 * j + 1) * 193 + 128 + e];
        p[j] = (a & 0xffffu) | (bv << 16);
      }
      uint4 pv = {p[0], p[1], p[2], p[3]};
      const int n0 = nb + nc * 8;
      const int kt = n0 >> 6, sub = n0 & 63;
      const int ks = sub >> 4, hh = (sub >> 3) & 1;
      const int dt = e >> 5, lv = e & 31;
      *(uint4*)(Vb + (size_t)bb * 262144 +
                ((((kt * 4 + ks) * 2 + hh) * 2 + dt) * 256 + lv * 8)) = pv;
    }
  }
}

// ---------------------------------------------------------------------------
// Kernel 2: flash attention partials. 1024 blocks x 256 thr (4 waves of
// 32 q). BARRIER-FREE: K/V frags direct from frag-ordered global (L2-hot,
// coalesced); waves free-run; loads overlap compute via compiler vmcnt.
// ---------------------------------------------------------------------------
__global__ __launch_bounds__(256, 3) void attn_kernel(
    const us* __restrict__ Qhi, const us* __restrict__ Qlo,
    const us* __restrict__ Kbh, const us* __restrict__ Kbl,
    const us* __restrict__ Vb,
    us* __restrict__ Opart, float* __restrict__ Mpart,
    float* __restrict__ Lpart)
{
  __shared__ float fb[4][2112];    // per-wave epilogue bounce
  __shared__ float alds[4][32];

  // XCD-aware map: XCD x serves batch x>>1
  const int bx = blockIdx.x;
  const int xc = bx & 7, b = xc >> 1;
  const int idx = ((bx >> 3) << 1) | (xc & 1);      // 0..255
  const int seg = idx & (NSEG - 1), qg = idx >> 3;  // seg 0..7, qg 0..31
  const int t = threadIdx.x;
  const int wid = t >> 6, lane = t & 63;
  const int l31 = lane & 31, h = lane >> 5;
  const int q0 = qg * 128 + wid * 32;               // wave's first q
  const int u = (b * 4096 + q0) >> 5;               // global 32q unit
  const size_t pb = (size_t)u * NSEG + seg;

  // persistent Q B-frags: n=l31, k=16ks+8h+j
  bf16x8 qh[4], ql[4];
  {
    const size_t rg = (size_t)(b * 4096 + q0 + l31) * 64;
    #pragma unroll
    for (int ks = 0; ks < 4; ++ks) {
      qh[ks] = *(const bf16x8*)(Qhi + rg + ks * 16 + h * 8);
      ql[ks] = *(const bf16x8*)(Qlo + rg + ks * 16 + h * 8);
    }
  }
  const size_t kbase = (size_t)b * 262144;    // Kb / Vb per-batch base

  f32x16 o[2] = {};
  float mrun = -__builtin_inff();
  float lrun = 0.f;

  for (int it = 0; it < ITERS; ++it) {
    const int KT = seg * ITERS + it;          // global 64-key tile id
    const size_t tb = kbase + (size_t)KT * 4096;

    // S^T = K_tile · Q^T (3-pass hi/lo). K A-frags direct from global:
    // lane (h,l31) reads tb + (ks*4+2h+m)*256 + l31*8 — 2x512B contiguous.
    f32x16 s[2] = {};
    #pragma unroll
    for (int m = 0; m < 2; ++m) {
      bf16x8 ah[4], al[4];
      #pragma unroll
      for (int ks = 0; ks < 4; ++ks) {
        const size_t ko = tb + (size_t)(ks * 4 + 2 * h + m) * 256 + l31 * 8;
        ah[ks] = *(const bf16x8*)(Kbh + ko);
        al[ks] = *(const bf16x8*)(Kbl + ko);
      }
      #pragma unroll
      for (int ks = 0; ks < 4; ++ks) {
        s[m] = mfma(ah[ks], qh[ks], s[m]);
        s[m] = mfma(al[ks], qh[ks], s[m]);
        s[m] = mfma(ah[ks], ql[ks], s[m]);
      }
    }

    // V B-frags (issued before softmax so latency hides behind it)
    bf16x8 vf0[4], vf1[4];
    #pragma unroll
    for (int ks = 0; ks < 4; ++ks) {
      const size_t vo = kbase + (size_t)(((KT * 4 + ks) * 2 + h) * 2) * 256 +
                        l31 * 8;
      vf0[ks] = *(const bf16x8*)(Vb + vo);
      vf1[ks] = *(const bf16x8*)(Vb + vo + 256);
    }

    // tile max (lane owns q=l31; partner xor-32 has the other 32 keys)
    float vm = -__builtin_inff();
    #pragma unroll
    for (int r = 0; r < 16; ++r)
      vm = fmaxf(vm, fmaxf(s[0][r], s[1][r]));
    vm = fmaxf(vm, __shfl_xor(vm, 32));

    // near-one-hot skip: tile contributes < 2^-24 of lrun -> drop it
    if (!__all(vm <= mrun - 24.f)) {
      // rescale tolerance: only adopt a higher max if it rose by > 0.5
      const float mnew = (vm > mrun + 0.5f) ? vm : mrun;
      const float alpha = EXP2(mrun - mnew);    // 1.0 when mnew==mrun
      float sum = 0.f;
      unsigned pp[2][8];
      #pragma unroll
      for (int m = 0; m < 2; ++m) {
        #pragma unroll
        for (int p = 0; p < 8; ++p) {
          const float p0 = EXP2(s[m][2 * p] - mnew);
          const float p1 = EXP2(s[m][2 * p + 1] - mnew);
          sum += p0 + p1;
          pp[m][p] = pk2t(p0, p1);              // one v_perm per pair
        }
      }
      sum += __shfl_xor(sum, 32);
      lrun = lrun * alpha + sum;
      mrun = mnew;

      // rescale O (rare; alds broadcast to C-layout rows; per-wave LDS)
      if (__any(alpha != 1.f)) {
        if (!h) alds[wid][l31] = alpha;
        #pragma unroll
        for (int g = 0; g < 4; ++g) {
          const float4 af4 = *(const float4*)(&alds[wid][8 * g + 4 * h]);
          #pragma unroll
          for (int rr = 0; rr < 4; ++rr) {
            const int r = 4 * g + rr;
            const float a = (rr == 0) ? af4.x : (rr == 1) ? af4.y
                           : (rr == 2) ? af4.z : af4.w;
            o[0][r] *= a;
            o[1][r] *= a;
          }
        }
      }

      // PV: P A-frags via shfl_xor(32) pair exchange; V frags from regs.
      #pragma unroll
      for (int ks = 0; ks < 4; ++ks) {
        const int m = ks >> 1, base = 4 * (ks & 1);
        const unsigned x0 = pp[m][base + 0], x1 = pp[m][base + 1];
        const unsigned x2 = pp[m][base + 2], x3 = pp[m][base + 3];
        const unsigned sA = h ? x0 : x2;
        const unsigned sB = h ? x1 : x3;
        const unsigned rA = (unsigned)__shfl_xor((int)sA, 32);
        const unsigned rB = (unsigned)__shfl_xor((int)sB, 32);
        u32x4 wv;
        wv.x = h ? rA : x0;
        wv.y = h ? rB : x1;
        wv.z = h ? x2 : rA;
        wv.w = h ? x3 : rB;
        const bf16x8 af = __builtin_bit_cast(bf16x8, wv);
        o[0] = mfma(af, vf0[ks], o[0]);
        o[1] = mfma(af, vf1[ks], o[1]);
      }
    }
  }

  // epilogue: O -> bf16 Opart via per-wave LDS bounce, dwordx4 stores.
  float* fw = fb[wid];
  #pragma unroll
  for (int dt = 0; dt < 2; ++dt) {
    #pragma unroll
    for (int r = 0; r < 16; ++r) {
      const int qrow = (r & 3) + 8 * (r >> 2) + 4 * h;  // 0..31
      fw[qrow * 66 + l31 + 32 * dt] = o[dt][r];
    }
  }
  #pragma unroll
  for (int jj = 0; jj < 4; ++jj) {
    const int chunk = lane + 64 * jj;           // 0..255
    const int rw = chunk >> 3, part = chunk & 7;
    const float* src = &fw[rw * 66 + part * 8];
    float2 a0 = *(const float2*)(src + 0);
    float2 a1 = *(const float2*)(src + 2);
    float2 a2 = *(const float2*)(src + 4);
    float2 a3 = *(const float2*)(src + 6);
    uint4 pkv;
    pkv.x = pk2t(a0.x, a0.y);
    pkv.y = pk2t(a1.x, a1.y);
    pkv.z = pk2t(a2.x, a2.y);
    pkv.w = pk2t(a3.x, a3.y);
    *(uint4*)(Opart + pb * 2048 + (size_t)rw * 64 + part * 8) = pkv;
  }
  if (!h) {
    Mpart[pb * 32 + l31] = mrun;
    Lpart[pb * 32 + l31] = lrun;
  }
}

// ---------------------------------------------------------------------------
// Kernel 3: merge 8 key-segment partials (bf16). 131072 thr, 8 d each.
// ---------------------------------------------------------------------------
__global__ __launch_bounds__(256, 1) void merge_kernel(
    const us* __restrict__ Opart, const float* __restrict__ Mpart,
    const float* __restrict__ Lpart, float* __restrict__ out)
{
  const int tg = blockIdx.x * 256 + threadIdx.x;
  const int q = tg >> 3, dc = (tg & 7) * 8;
  const int u = q >> 5, ql = q & 31;
  const int base = u * NSEG;
  float M = -__builtin_inff();
  #pragma unroll
  for (int s = 0; s < NSEG; ++s)
    M = fmaxf(M, Mpart[(size_t)(base + s) * 32 + ql]);
  float acc[8] = {};
  float den = 0.f;
  #pragma unroll
  for (int s = 0; s < NSEG; ++s) {
    const float wgt = EXP2(Mpart[(size_t)(base + s) * 32 + ql] - M);
    den += wgt * Lpart[(size_t)(base + s) * 32 + ql];
    const uint4 r = *(const uint4*)(Opart + (size_t)(base + s) * 2048 +
                                    ql * 64 + dc);
    const unsigned rw[4] = {r.x, r.y, r.z, r.w};
    #pragma unroll
    for (int j = 0; j < 4; ++j) {
      acc[2 * j]     += wgt * bf2f((us)(rw[j] & 0xffffu));
      acc[2 * j + 1] += wgt * bf2f((us)(rw[j] >> 16));
    }
  }
  const float inv = 1.f / den;
  float4 r0 = {acc[0] * inv, acc[1] * inv, acc[2] * inv, acc[3] * inv};
  float4 r1 = {acc[4] * inv, acc[5] * inv, acc[6] * inv, acc[7] * inv};
  *(float4*)(out + (size_t)q * 64 + dc) = r0;
  *(float4*)(out + (size_t)q * 64 + dc + 4) = r1;
}

// ---------------------------------------------------------------------------
extern "C" void kernel_launch(void* const* d_in, const int* in_sizes, int n_in,
                              void* d_out, int out_size, void* d_ws,
                              size_t ws_size, hipStream_t stream)
{
  const float* x = (const float*)d_in[0];
  const float* w = (const float*)d_in[1];
  float* out = (float*)d_out;
  char* ws = (char*)d_ws;

  const size_t T = 2097152;  // bytes per bf16 [4,4096,64] tensor
  us* Qhi = (us*)(ws + 0 * T);
  us* Qlo = (us*)(ws + 1 * T);
  us* Kbh = (us*)(ws + 2 * T);
  us* Kbl = (us*)(ws + 3 * T);
  us* Vb  = (us*)(ws + 4 * T);
  us* Wbh = (us*)(ws + 5 * T);                    // 49,152 B
  us* Wbl = (us*)(ws + 5 * T + 49152);            // 49,152 B
  char* pbase = ws + 5 * T + 98304;
  us* Opart = (us*)pbase;                                    // 16,777,216 B
  float* Mpart = (float*)(pbase + 16777216);                 //    524,288 B
  float* Lpart = (float*)(pbase + 16777216 + 524288);        //    524,288 B
  // total workspace use: ~28.4 MiB

  hipLaunchKernelGGL(wprep_kernel, dim3(96), dim3(256), 0, stream,
                     w, Wbh, Wbl);
  hipLaunchKernelGGL(qkv_kernel, dim3(512), dim3(384), 0, stream,
                     x, Wbh, Wbl, Qhi, Qlo, Kbh, Kbl, Vb);
  hipLaunchKernelGGL(attn_kernel, dim3(1024), dim3(256), 0, stream,
                     Qhi, Qlo, Kbh, Kbl, Vb, Opart, Mpart, Lpart);
  hipLaunchKernelGGL(merge_kernel, dim3(512), dim3(256), 0, stream,
                     Opart, Mpart, Lpart, out);
}